// Round 2
// baseline (648.991 us; speedup 1.0000x reference)
//
#include <hip/hip_runtime.h>

// ---------------------------------------------------------------------------
// Soft decision tree forward:
//   d = sigmoid(X @ T^T); leaf probs = depth-10 path products;
//   out = softmax(probs @ L)
//
// GEMM1 = 3-term bf16 split expressed as one K=3072 GEMM over segment bases
// A=[Xhi|Xlo|Xhi], B=[Thi|Thi|Tlo]. GEMM2 plain bf16 K=1024.
// Both use a 256x256-tile, 8-wave, BK=32, 4-slot-LDS-ring pipelined kernel:
// counted vmcnt(8) (never 0 in main loop), 1 barrier/phase, T2 swizzle,
// setprio around the MFMA cluster, bijective XCD block swizzle.
// ---------------------------------------------------------------------------

typedef unsigned short u16;
typedef short bf16x8 __attribute__((ext_vector_type(8)));
typedef float f32x4 __attribute__((ext_vector_type(4)));

#define BATCH 32768
#define DIM   1024
#define NPAD  1024

// ---- bf16 helpers (RN-even) ----
__device__ __forceinline__ u16 f2bf(float f) {
    union { float f; unsigned u; } v; v.f = f;
    unsigned r = v.u + 0x7FFFu + ((v.u >> 16) & 1u);
    return (u16)(r >> 16);
}
__device__ __forceinline__ float bf2f(u16 h) {
    union { unsigned u; float f; } v; v.u = ((unsigned)h) << 16;
    return v.f;
}

// ---- async global->LDS, 16B/lane (dest = wave-uniform base + lane*16) ----
__device__ __forceinline__ void gl16(const u16* g, char* l) {
    __builtin_amdgcn_global_load_lds(
        (const __attribute__((address_space(1))) unsigned int*)g,
        (__attribute__((address_space(3))) unsigned int*)l, 16, 0, 0);
}

// ---- LDS byte swizzle within a 16KB [256 rows][32 bf16] slot ----
// Involutive (reads bits 8:7, flips bits 5:4), preserves 16B blocks.
// Column-slice reads at 64B row stride spread across 8 bank-quads (2-way).
__device__ __forceinline__ unsigned swz(unsigned o) {
    return o ^ (((o >> 7) & 3u) << 4);
}

__device__ __forceinline__ void wait_vm8() { asm volatile("s_waitcnt vmcnt(8)" ::: "memory"); }
__device__ __forceinline__ void wait_vm4() { asm volatile("s_waitcnt vmcnt(4)" ::: "memory"); }
__device__ __forceinline__ void wait_vm0() { asm volatile("s_waitcnt vmcnt(0)" ::: "memory"); }
__device__ __forceinline__ void barrier_raw() { asm volatile("s_barrier" ::: "memory"); }

// ---------------------------------------------------------------------------
// prep kernels (unchanged from round 1 — near-BW-bound)
// ---------------------------------------------------------------------------
__global__ __launch_bounds__(256) void prep_x(const float4* __restrict__ x4,
                                              u16* __restrict__ xhi,
                                              u16* __restrict__ xlo, int n4) {
    int stride = gridDim.x * blockDim.x;
    for (int i = blockIdx.x * blockDim.x + threadIdx.x; i < n4; i += stride) {
        float4 v = x4[i];
        u16 h0 = f2bf(v.x), h1 = f2bf(v.y), h2 = f2bf(v.z), h3 = f2bf(v.w);
        u16 l0 = f2bf(v.x - bf2f(h0)), l1 = f2bf(v.y - bf2f(h1));
        u16 l2 = f2bf(v.z - bf2f(h2)), l3 = f2bf(v.w - bf2f(h3));
        *(ushort4*)&xhi[(size_t)i * 4] = make_ushort4(h0, h1, h2, h3);
        *(ushort4*)&xlo[(size_t)i * 4] = make_ushort4(l0, l1, l2, l3);
    }
}

__global__ __launch_bounds__(256) void prep_t(const float* __restrict__ t,
                                              u16* __restrict__ thi,
                                              u16* __restrict__ tlo) {
    int i = blockIdx.x * 256 + threadIdx.x;
    int node = i >> 10;
    float v = (node < 1023) ? t[i] : 0.0f;
    u16 h = f2bf(v);
    thi[i] = h;
    tlo[i] = f2bf(v - bf2f(h));
}

__global__ __launch_bounds__(256) void prep_lt(const float* __restrict__ L,
                                               u16* __restrict__ LT) {
    __shared__ float tile[32][33];
    int bx = blockIdx.x, by = blockIdx.y;
    int tx = threadIdx.x & 31, ty = threadIdx.x >> 5;
#pragma unroll
    for (int r = 0; r < 4; r++)
        tile[ty + 8 * r][tx] = L[(size_t)(by * 32 + ty + 8 * r) * 1024 + bx * 32 + tx];
    __syncthreads();
#pragma unroll
    for (int r = 0; r < 4; r++)
        LT[(size_t)(bx * 32 + ty + 8 * r) * 1024 + by * 32 + tx] =
            f2bf(tile[tx][ty + 8 * r]);
}

// ---------------------------------------------------------------------------
// 256x256-tile 8-wave pipelined GEMM core.
// A,B row-major [rows][1024] bf16 per segment; K = NT*32 over segments of 32
// subtiles. acc[8][4]: wave (wm,wn) owns rows wm*128+[0,128), cols wn*64+[0,64).
// LDS: A slots [0,64K), B slots [64K,128K); slot = 16KB [256][32] swizzled.
// ---------------------------------------------------------------------------
template <int NT>
__device__ __forceinline__ void gemm_core(
    const u16* A0p, const u16* A1p, const u16* A2p,
    const u16* B0p, const u16* B1p, const u16* B2p,
    int rb, int cb, char* lds, f32x4 acc[8][4])
{
    const int t = threadIdx.x, wid = t >> 6, lane = t & 63;
    const int wm = wid >> 2, wn = wid & 3;
    const int mr = lane & 15, kg = lane >> 4;

    // staging precompute: linear LDS byte o -> swizzled tile pos p -> global
    const unsigned o0 = t * 16, o1 = 8192 + t * 16;
    const unsigned p0 = swz(o0), p1 = swz(o1);
    const unsigned r0 = p0 >> 6, c0 = (p0 & 63) >> 1;
    const unsigned r1 = p1 >> 6, c1 = (p1 & 63) >> 1;
    const size_t gA0 = (size_t)(rb + (int)r0) * 1024 + c0;
    const size_t gA1 = (size_t)(rb + (int)r1) * 1024 + c1;
    const size_t gB0 = (size_t)(cb + (int)r0) * 1024 + c0;
    const size_t gB1 = (size_t)(cb + (int)r1) * 1024 + c1;
    char* ldsA = lds + (size_t)(wid * 1024);
    char* ldsB = lds + 65536 + (size_t)(wid * 1024);

    // ds_read byte offsets (within slot), swizzled
    unsigned swzA[8], swzB[4];
#pragma unroll
    for (int m = 0; m < 8; ++m)
        swzA[m] = swz((unsigned)((wm * 128 + m * 16 + mr) * 64 + kg * 16));
#pragma unroll
    for (int n = 0; n < 4; ++n)
        swzB[n] = swz((unsigned)((wn * 64 + n * 16 + mr) * 64 + kg * 16));

#pragma unroll
    for (int m = 0; m < 8; ++m)
#pragma unroll
        for (int n = 0; n < 4; ++n) acc[m][n] = (f32x4){0.f, 0.f, 0.f, 0.f};

    auto stage = [&](int j) {
        const int seg = j >> 5;
        const int kk = (j & 31) * 32;
        const u16* As = (seg == 0) ? A0p : ((seg == 1) ? A1p : A2p);
        const u16* Bs = (seg == 0) ? B0p : ((seg == 1) ? B1p : B2p);
        const int so = (j & 3) * 16384;
        gl16(As + gA0 + kk, ldsA + so);
        gl16(As + gA1 + kk, ldsA + so + 8192);
        gl16(Bs + gB0 + kk, ldsB + so);
        gl16(Bs + gB1 + kk, ldsB + so + 8192);
    };

    // prologue: 3 subtiles in flight (12 loads/thread)
    stage(0); stage(1); stage(2);

    auto phase = [&](int j, int vm, bool di) {
        // gate: own 4 loads of subtile j landed (counted, never stalls deep)
        if (vm == 8) wait_vm8();
        else if (vm == 4) wait_vm4();
        else wait_vm0();
        // all waves landed subtile j; all waves done reading slot (j-1)&3
        barrier_raw();
        if (di) stage(j + 3);            // refill the slot freed last phase
        const int so = (j & 3) * 16384;
        bf16x8 a[8], b[4];
#pragma unroll
        for (int m = 0; m < 8; ++m)
            a[m] = *(const bf16x8*)(lds + so + swzA[m]);
#pragma unroll
        for (int n = 0; n < 4; ++n)
            b[n] = *(const bf16x8*)(lds + 65536 + so + swzB[n]);
        __builtin_amdgcn_s_setprio(1);
#pragma unroll
        for (int m = 0; m < 8; ++m)
#pragma unroll
            for (int n = 0; n < 4; ++n)
                acc[m][n] = __builtin_amdgcn_mfma_f32_16x16x32_bf16(a[m], b[n], acc[m][n], 0, 0, 0);
        __builtin_amdgcn_s_setprio(0);
    };

#pragma unroll 1
    for (int j = 0; j < NT - 3; ++j) phase(j, 8, true);
    phase(NT - 3, 8, false);
    phase(NT - 2, 4, false);
    phase(NT - 1, 0, false);
}

// bijective XCD swizzle for 512 blocks (512 % 8 == 0): XCD x gets a
// contiguous chunk of logical ids -> same-row col-blocks share the XCD L2.
__device__ __forceinline__ void block_map(int bid, int& rb, int& cb) {
    int lid = (bid & 7) * 64 + (bid >> 3);
    rb = (lid >> 2) * 256;
    cb = (lid & 3) * 256;
}

// ---------------------------------------------------------------------------
// GEMM1: K=3072 over A=[Xhi|Xlo|Xhi], B=[Thi|Thi|Tlo]; sigmoid epilogue
// ---------------------------------------------------------------------------
__global__ __launch_bounds__(512, 2) void gemm1_8p(
    const u16* __restrict__ Xhi, const u16* __restrict__ Xlo,
    const u16* __restrict__ Thi, const u16* __restrict__ Tlo,
    ushort2* __restrict__ dpair)
{
    __shared__ __align__(16) char lds[131072];
    int rb, cb;
    block_map(blockIdx.x, rb, cb);
    f32x4 acc[8][4];
    gemm_core<96>(Xhi, Xlo, Xhi, Thi, Thi, Tlo, rb, cb, lds, acc);

    const int lane = threadIdx.x & 63, wid = threadIdx.x >> 6;
    const int wm = wid >> 2, wn = wid & 3;
    const int mr = lane & 15, fq = (lane >> 4) * 4;
#pragma unroll
    for (int m = 0; m < 8; ++m)
#pragma unroll
        for (int j = 0; j < 4; ++j) {
            int grow = rb + wm * 128 + m * 16 + fq + j;
#pragma unroll
            for (int n = 0; n < 4; ++n) {
                int gcol = cb + wn * 64 + n * 16 + mr;
                float s = acc[m][n][j];
                float d = 1.0f / (1.0f + __expf(-s));
                dpair[(size_t)grow * NPAD + gcol] = make_ushort2(f2bf(d), f2bf(1.0f - d));
            }
        }
}

// ---------------------------------------------------------------------------
// GEMM2: logits = probs @ LT^T (K=1024), f32 epilogue
// ---------------------------------------------------------------------------
__global__ __launch_bounds__(512, 2) void gemm2_8p(
    const u16* __restrict__ P, const u16* __restrict__ LT,
    float* __restrict__ out)
{
    __shared__ __align__(16) char lds[131072];
    int rb, cb;
    block_map(blockIdx.x, rb, cb);
    f32x4 acc[8][4];
    gemm_core<32>(P, P, P, LT, LT, LT, rb, cb, lds, acc);

    const int lane = threadIdx.x & 63, wid = threadIdx.x >> 6;
    const int wm = wid >> 2, wn = wid & 3;
    const int mr = lane & 15, fq = (lane >> 4) * 4;
#pragma unroll
    for (int m = 0; m < 8; ++m)
#pragma unroll
        for (int j = 0; j < 4; ++j) {
            int grow = rb + wm * 128 + m * 16 + fq + j;
#pragma unroll
            for (int n = 0; n < 4; ++n) {
                int gcol = cb + wn * 64 + n * 16 + mr;
                out[(size_t)grow * 1024 + gcol] = acc[m][n][j];
            }
        }
}

// ---------------------------------------------------------------------------
// tree expansion: one wave per row; lane l owns leaves l*16 .. l*16+15
// ---------------------------------------------------------------------------
__global__ __launch_bounds__(256) void probs_kernel(const ushort2* __restrict__ dpair,
                                                    u16* __restrict__ probs) {
    const int t = threadIdx.x, w = t >> 6, l = t & 63;
    const int row = (blockIdx.x << 2) + w;
    const ushort2* dp = dpair + (size_t)row * NPAD;

    float prod = 1.0f;
#pragma unroll
    for (int lev = 0; lev < 6; lev++) {
        int node = (1 << lev) - 1 + (l >> (6 - lev));
        int bit  = (l >> (5 - lev)) & 1;
        ushort2 v = dp[node];
        prod *= bf2f(bit ? v.y : v.x);
    }
    ushort2 n6 = dp[63 + l];
    ushort2 n7[2], n8[4], n9[8];
#pragma unroll
    for (int j = 0; j < 2; j++) n7[j] = dp[127 + 2 * l + j];
#pragma unroll
    for (int j = 0; j < 4; j++) n8[j] = dp[255 + 4 * l + j];
#pragma unroll
    for (int j = 0; j < 8; j++) n9[j] = dp[511 + 8 * l + j];

    u16 outv[16];
#pragma unroll
    for (int j = 0; j < 16; j++) {
        float f6 = bf2f((j >> 3) ? n6.y : n6.x);
        ushort2 v7 = n7[j >> 3];       float f7 = bf2f(((j >> 2) & 1) ? v7.y : v7.x);
        ushort2 v8 = n8[j >> 2];       float f8 = bf2f(((j >> 1) & 1) ? v8.y : v8.x);
        ushort2 v9 = n9[j >> 1];       float f9 = bf2f((j & 1) ? v9.y : v9.x);
        outv[j] = f2bf(prod * f6 * f7 * f8 * f9);
    }
    ushort4* po = (ushort4*)(probs + (size_t)row * 1024 + (l << 4));
#pragma unroll
    for (int q = 0; q < 4; q++)
        po[q] = make_ushort4(outv[4 * q], outv[4 * q + 1], outv[4 * q + 2], outv[4 * q + 3]);
}

// ---------------------------------------------------------------------------
// row softmax in-place on d_out
// ---------------------------------------------------------------------------
__global__ __launch_bounds__(256) void softmax_kernel(float* __restrict__ out) {
    __shared__ float red[8];
    const int t = threadIdx.x, w = t >> 6, l = t & 63;
    float4* o4 = (float4*)out;
    const size_t base = (size_t)blockIdx.x * 256;
    float4 v = o4[base + t];

    float m = fmaxf(fmaxf(v.x, v.y), fmaxf(v.z, v.w));
#pragma unroll
    for (int off = 32; off; off >>= 1) m = fmaxf(m, __shfl_xor(m, off));
    if (l == 0) red[w] = m;
    __syncthreads();
    m = fmaxf(fmaxf(red[0], red[1]), fmaxf(red[2], red[3]));

    float e0 = __expf(v.x - m), e1 = __expf(v.y - m);
    float e2 = __expf(v.z - m), e3 = __expf(v.w - m);
    float s = e0 + e1 + e2 + e3;
#pragma unroll
    for (int off = 32; off; off >>= 1) s += __shfl_xor(s, off);
    if (l == 0) red[4 + w] = s;
    __syncthreads();
    s = red[4] + red[5] + red[6] + red[7];
    float inv = 1.0f / s;
    o4[base + t] = make_float4(e0 * inv, e1 * inv, e2 * inv, e3 * inv);
}

// ---------------------------------------------------------------------------
extern "C" void kernel_launch(void* const* d_in, const int* in_sizes, int n_in,
                              void* d_out, int out_size, void* d_ws, size_t ws_size,
                              hipStream_t stream) {
    const float* x  = (const float*)d_in[0];
    const float* ft = (const float*)d_in[1];
    const float* lp = (const float*)d_in[2];
    float* out = (float*)d_out;
    char* ws = (char*)d_ws;

    // ws layout: Xhi 64Mi | Xlo 64Mi | Thi 2Mi | Tlo 2Mi | LT 2Mi | dpair 128Mi | probs 64Mi
    u16* Xhi = (u16*)ws;
    u16* Xlo = Xhi + (size_t)BATCH * DIM;
    u16* Thi = (u16*)(ws + (size_t)134217728);
    u16* Tlo = Thi + (size_t)NPAD * DIM;
    u16* LT  = Tlo + (size_t)NPAD * DIM;
    ushort2* dpair = (ushort2*)(ws + (size_t)134217728 + 3 * 2097152);
    u16* probs = (u16*)(ws + (size_t)134217728 + 3 * 2097152 + (size_t)BATCH * NPAD * 4);

    prep_x<<<4096, 256, 0, stream>>>((const float4*)x, Xhi, Xlo, BATCH * DIM / 4);
    prep_t<<<4096, 256, 0, stream>>>(ft, Thi, Tlo);
    prep_lt<<<dim3(32, 32), 256, 0, stream>>>(lp, LT);
    gemm1_8p<<<512, 512, 0, stream>>>(Xhi, Xlo, Thi, Tlo, dpair);
    probs_kernel<<<8192, 256, 0, stream>>>(dpair, probs);
    gemm2_8p<<<512, 512, 0, stream>>>(probs, LT, out);
    softmax_kernel<<<32768, 256, 0, stream>>>(out);
}

// Round 3
// 310.414 us; speedup vs baseline: 2.0907x; 2.0907x over previous
//
#include <hip/hip_runtime.h>

// ---------------------------------------------------------------------------
// Soft decision tree forward (all-f16 pipeline):
//   d = sigmoid(X @ T^T); leaf probs = depth-10 path products;
//   out = softmax(probs @ L)
//
// GEMM1: plain f16 single-term (f16 dot error ~0.013 pre-sigmoid; only
// borderline nodes transmit it). GEMM2: f16. d/probs/L stored f16 (4x better
// than round-1 bf16). Both GEMMs use the PROVEN m97 128x128-tile 2-barrier
// structure (round-1: 895 TF) + bijective XCD block swizzle.
// ---------------------------------------------------------------------------

typedef unsigned short u16;
typedef _Float16 f16;
typedef _Float16 f16x8 __attribute__((ext_vector_type(8)));
typedef float f32x4 __attribute__((ext_vector_type(4)));

#define BATCH 32768
#define DIM   1024
#define NPAD  1024

// ---- f16 helpers ----
__device__ __forceinline__ u16 f2h(float f) {
    union { f16 h; u16 u; } v; v.h = (f16)f; return v.u;
}
__device__ __forceinline__ float h2f(u16 u) {
    union { u16 u; f16 h; } v; v.u = u; return (float)v.h;
}

// ---- async global->LDS, 16B/lane (dest = wave-uniform base + lane*16) ----
__device__ __forceinline__ void gl16(const u16* g, u16* l) {
    __builtin_amdgcn_global_load_lds(
        (const __attribute__((address_space(1))) unsigned int*)g,
        (__attribute__((address_space(3))) unsigned int*)l, 16, 0, 0);
}

// ---------------------------------------------------------------------------
// prep: X f32 -> Xh f16
// ---------------------------------------------------------------------------
__global__ __launch_bounds__(256) void prep_x(const float4* __restrict__ x4,
                                              u16* __restrict__ xh, int n4) {
    int stride = gridDim.x * blockDim.x;
    for (int i = blockIdx.x * blockDim.x + threadIdx.x; i < n4; i += stride) {
        float4 v = x4[i];
        *(ushort4*)&xh[(size_t)i * 4] =
            make_ushort4(f2h(v.x), f2h(v.y), f2h(v.z), f2h(v.w));
    }
}

// ---------------------------------------------------------------------------
// prep: thresholds (1023x1024 f32) -> Th f16 [1024][1024], row 1023 = 0
// ---------------------------------------------------------------------------
__global__ __launch_bounds__(256) void prep_t(const float* __restrict__ t,
                                              u16* __restrict__ th) {
    int i = blockIdx.x * 256 + threadIdx.x;
    int node = i >> 10;
    float v = (node < 1023) ? t[i] : 0.0f;
    th[i] = f2h(v);
}

// ---------------------------------------------------------------------------
// prep: leaf_predictions (1024x1024 f32) -> LT f16 transposed [out][leaf]
// ---------------------------------------------------------------------------
__global__ __launch_bounds__(256) void prep_lt(const float* __restrict__ L,
                                               u16* __restrict__ LT) {
    __shared__ float tile[32][33];
    int bx = blockIdx.x, by = blockIdx.y;
    int tx = threadIdx.x & 31, ty = threadIdx.x >> 5;
#pragma unroll
    for (int r = 0; r < 4; r++)
        tile[ty + 8 * r][tx] = L[(size_t)(by * 32 + ty + 8 * r) * 1024 + bx * 32 + tx];
    __syncthreads();
#pragma unroll
    for (int r = 0; r < 4; r++)
        LT[(size_t)(bx * 32 + ty + 8 * r) * 1024 + by * 32 + tx] =
            f2h(tile[tx][ty + 8 * r]);
}

// bijective XCD swizzle for 2048 blocks (2048 % 8 == 0): XCD x gets 256
// consecutive logical ids -> row-panels stay on one XCD's L2 across their
// 8 col-tiles.
__device__ __forceinline__ void block_map(int bid, int& rb, int& cb) {
    int lid = (bid & 7) * 256 + (bid >> 3);
    rb = (lid >> 3) << 7;
    cb = (lid & 7) << 7;
}

// ---------------------------------------------------------------------------
// GEMM1 (plain f16) + sigmoid -> dpair {d, 1-d} f16x2
// m97 structure: 128x128 tile, BK=32, 4 waves each 64x64 (4x4 frags 16x16x32)
// ---------------------------------------------------------------------------
__global__ __launch_bounds__(256, 2) void gemm1_kernel(
    const u16* __restrict__ Xh, const u16* __restrict__ Th,
    ushort2* __restrict__ dpair) {
    __shared__ __align__(16) u16 sA[4096], sB[4096];

    const int t = threadIdx.x, w = t >> 6, l = t & 63;
    int rb, cb;
    block_map(blockIdx.x, rb, cb);

    const int r0  = (w << 5) + (l >> 2);
    const int seg = (l & 3) << 3;
    const size_t gA0 = (size_t)(rb + r0) * DIM + seg;
    const size_t gA1 = gA0 + (size_t)16 * DIM;
    const size_t gB0 = (size_t)(cb + r0) * DIM + seg;
    const size_t gB1 = gB0 + (size_t)16 * DIM;
    const int ld0 = w << 10;
    const int ld1 = ld0 + 512;

    f32x4 acc[4][4];
#pragma unroll
    for (int m = 0; m < 4; m++)
#pragma unroll
        for (int n = 0; n < 4; n++) acc[m][n] = (f32x4){0.f, 0.f, 0.f, 0.f};

    const int wm = w >> 1, wn = w & 1;
    const int g8 = (l >> 4) << 3;
    const int mr = l & 15;

    for (int k0 = 0; k0 < DIM; k0 += 32) {
        gl16(Xh + gA0 + k0, sA + ld0);
        gl16(Xh + gA1 + k0, sA + ld1);
        gl16(Th + gB0 + k0, sB + ld0);
        gl16(Th + gB1 + k0, sB + ld1);
        __syncthreads();

        f16x8 a[4], b[4];
#pragma unroll
        for (int m = 0; m < 4; m++)
            a[m] = *(const f16x8*)(sA + ((wm << 6) + (m << 4) + mr) * 32 + g8);
#pragma unroll
        for (int n = 0; n < 4; n++)
            b[n] = *(const f16x8*)(sB + ((wn << 6) + (n << 4) + mr) * 32 + g8);
#pragma unroll
        for (int m = 0; m < 4; m++)
#pragma unroll
            for (int n = 0; n < 4; n++)
                acc[m][n] = __builtin_amdgcn_mfma_f32_16x16x32_f16(a[m], b[n], acc[m][n], 0, 0, 0);
        __syncthreads();
    }

    const int fq = (l >> 4) << 2;
#pragma unroll
    for (int m = 0; m < 4; m++)
#pragma unroll
        for (int j = 0; j < 4; j++) {
            int grow = rb + (wm << 6) + (m << 4) + fq + j;
#pragma unroll
            for (int n = 0; n < 4; n++) {
                int gcol = cb + (wn << 6) + (n << 4) + mr;
                float s = acc[m][n][j];
                float d = 1.0f / (1.0f + __expf(-s));
                dpair[(size_t)grow * NPAD + gcol] = make_ushort2(f2h(d), f2h(1.0f - d));
            }
        }
}

// ---------------------------------------------------------------------------
// tree expansion: one wave per row; lane l owns leaves l*16 .. l*16+15
// ---------------------------------------------------------------------------
__global__ __launch_bounds__(256) void probs_kernel(const ushort2* __restrict__ dpair,
                                                    u16* __restrict__ probs) {
    const int t = threadIdx.x, w = t >> 6, l = t & 63;
    const int row = (blockIdx.x << 2) + w;
    const ushort2* dp = dpair + (size_t)row * NPAD;

    float prod = 1.0f;
#pragma unroll
    for (int lev = 0; lev < 6; lev++) {
        int node = (1 << lev) - 1 + (l >> (6 - lev));
        int bit  = (l >> (5 - lev)) & 1;
        ushort2 v = dp[node];
        prod *= h2f(bit ? v.y : v.x);
    }
    ushort2 n6 = dp[63 + l];
    ushort2 n7[2], n8[4], n9[8];
#pragma unroll
    for (int j = 0; j < 2; j++) n7[j] = dp[127 + 2 * l + j];
#pragma unroll
    for (int j = 0; j < 4; j++) n8[j] = dp[255 + 4 * l + j];
#pragma unroll
    for (int j = 0; j < 8; j++) n9[j] = dp[511 + 8 * l + j];

    u16 outv[16];
#pragma unroll
    for (int j = 0; j < 16; j++) {
        float f6 = h2f((j >> 3) ? n6.y : n6.x);
        ushort2 v7 = n7[j >> 3];       float f7 = h2f(((j >> 2) & 1) ? v7.y : v7.x);
        ushort2 v8 = n8[j >> 2];       float f8 = h2f(((j >> 1) & 1) ? v8.y : v8.x);
        ushort2 v9 = n9[j >> 1];       float f9 = h2f((j & 1) ? v9.y : v9.x);
        outv[j] = f2h(prod * f6 * f7 * f8 * f9);
    }
    ushort4* po = (ushort4*)(probs + (size_t)row * 1024 + (l << 4));
#pragma unroll
    for (int q = 0; q < 4; q++)
        po[q] = make_ushort4(outv[4 * q], outv[4 * q + 1], outv[4 * q + 2], outv[4 * q + 3]);
}

// ---------------------------------------------------------------------------
// GEMM2 (f16): logits = probs @ LT^T -> d_out (f32)
// ---------------------------------------------------------------------------
__global__ __launch_bounds__(256, 2) void gemm2_kernel(
    const u16* __restrict__ P, const u16* __restrict__ LT, float* __restrict__ out) {
    __shared__ __align__(16) u16 sA[4096], sB[4096];

    const int t = threadIdx.x, w = t >> 6, l = t & 63;
    int rb, cb;
    block_map(blockIdx.x, rb, cb);

    const int r0  = (w << 5) + (l >> 2);
    const int seg = (l & 3) << 3;
    const size_t gA0 = (size_t)(rb + r0) * 1024 + seg;
    const size_t gA1 = gA0 + (size_t)16 * 1024;
    const size_t gB0 = (size_t)(cb + r0) * 1024 + seg;
    const size_t gB1 = gB0 + (size_t)16 * 1024;
    const int ld0 = w << 10, ld1 = (w << 10) + 512;

    f32x4 acc[4][4];
#pragma unroll
    for (int m = 0; m < 4; m++)
#pragma unroll
        for (int n = 0; n < 4; n++) acc[m][n] = (f32x4){0.f, 0.f, 0.f, 0.f};

    const int wm = w >> 1, wn = w & 1;
    const int g8 = (l >> 4) << 3;
    const int mr = l & 15;

    for (int k0 = 0; k0 < 1024; k0 += 32) {
        gl16(P + gA0 + k0, sA + ld0);
        gl16(P + gA1 + k0, sA + ld1);
        gl16(LT + gB0 + k0, sB + ld0);
        gl16(LT + gB1 + k0, sB + ld1);
        __syncthreads();

        f16x8 a[4], b[4];
#pragma unroll
        for (int m = 0; m < 4; m++)
            a[m] = *(const f16x8*)(sA + ((wm << 6) + (m << 4) + mr) * 32 + g8);
#pragma unroll
        for (int n = 0; n < 4; n++)
            b[n] = *(const f16x8*)(sB + ((wn << 6) + (n << 4) + mr) * 32 + g8);
#pragma unroll
        for (int m = 0; m < 4; m++)
#pragma unroll
            for (int n = 0; n < 4; n++)
                acc[m][n] = __builtin_amdgcn_mfma_f32_16x16x32_f16(a[m], b[n], acc[m][n], 0, 0, 0);
        __syncthreads();
    }

    const int fq = (l >> 4) << 2;
#pragma unroll
    for (int m = 0; m < 4; m++)
#pragma unroll
        for (int j = 0; j < 4; j++) {
            int grow = rb + (wm << 6) + (m << 4) + fq + j;
#pragma unroll
            for (int n = 0; n < 4; n++) {
                int gcol = cb + (wn << 6) + (n << 4) + mr;
                out[(size_t)grow * 1024 + gcol] = acc[m][n][j];
            }
        }
}

// ---------------------------------------------------------------------------
// row softmax in-place on d_out
// ---------------------------------------------------------------------------
__global__ __launch_bounds__(256) void softmax_kernel(float* __restrict__ out) {
    __shared__ float red[8];
    const int t = threadIdx.x, w = t >> 6, l = t & 63;
    float4* o4 = (float4*)out;
    const size_t base = (size_t)blockIdx.x * 256;
    float4 v = o4[base + t];

    float m = fmaxf(fmaxf(v.x, v.y), fmaxf(v.z, v.w));
#pragma unroll
    for (int off = 32; off; off >>= 1) m = fmaxf(m, __shfl_xor(m, off));
    if (l == 0) red[w] = m;
    __syncthreads();
    m = fmaxf(fmaxf(red[0], red[1]), fmaxf(red[2], red[3]));

    float e0 = __expf(v.x - m), e1 = __expf(v.y - m);
    float e2 = __expf(v.z - m), e3 = __expf(v.w - m);
    float s = e0 + e1 + e2 + e3;
#pragma unroll
    for (int off = 32; off; off >>= 1) s += __shfl_xor(s, off);
    if (l == 0) red[4 + w] = s;
    __syncthreads();
    s = red[4] + red[5] + red[6] + red[7];
    float inv = 1.0f / s;
    o4[base + t] = make_float4(e0 * inv, e1 * inv, e2 * inv, e3 * inv);
}

// ---------------------------------------------------------------------------
extern "C" void kernel_launch(void* const* d_in, const int* in_sizes, int n_in,
                              void* d_out, int out_size, void* d_ws, size_t ws_size,
                              hipStream_t stream) {
    const float* x  = (const float*)d_in[0];
    const float* ft = (const float*)d_in[1];
    const float* lp = (const float*)d_in[2];
    float* out = (float*)d_out;
    char* ws = (char*)d_ws;

    // ws layout: Xh 64Mi | Th 2Mi | LT 2Mi | dpair 128Mi | probs 64Mi
    u16* Xh = (u16*)ws;
    u16* Th = (u16*)(ws + (size_t)67108864);
    u16* LT = Th + (size_t)NPAD * DIM;
    ushort2* dpair = (ushort2*)(ws + (size_t)67108864 + 2 * 2097152);
    u16* probs = (u16*)(ws + (size_t)67108864 + 2 * 2097152 + (size_t)BATCH * NPAD * 4);

    prep_x<<<4096, 256, 0, stream>>>((const float4*)x, Xh, BATCH * DIM / 4);
    prep_t<<<4096, 256, 0, stream>>>(ft, Th);
    prep_lt<<<dim3(32, 32), 256, 0, stream>>>(lp, LT);
    gemm1_kernel<<<2048, 256, 0, stream>>>(Xh, Th, dpair);
    probs_kernel<<<8192, 256, 0, stream>>>(dpair, probs);
    gemm2_kernel<<<2048, 256, 0, stream>>>(probs, LT, out);
    softmax_kernel<<<32768, 256, 0, stream>>>(out);
}

// Round 4
// 271.979 us; speedup vs baseline: 2.3862x; 1.1413x over previous
//
#include <hip/hip_runtime.h>

// ---------------------------------------------------------------------------
// Soft decision tree forward (all-f16 pipeline):
//   d = sigmoid(X @ T^T); leaf probs = depth-10 path products;
//   out = softmax(probs @ L)
//
// GEMM1/GEMM2: 256x256-tile, BK=64, 8-wave (2Mx4N), 8-phase pipelined
// schedule (m201 template): 2 barriers/phase, counted vmcnt(4) once per
// K-tile, T2 row-XOR LDS swizzle (linear gl16 dest + pre-swizzled global
// source + swizzled ds_read), setprio around MFMA, bijective XCD swizzle.
// ---------------------------------------------------------------------------

typedef unsigned short u16;
typedef _Float16 f16;
typedef _Float16 f16x8 __attribute__((ext_vector_type(8)));
typedef float f32x4 __attribute__((ext_vector_type(4)));

#define BATCH 32768
#define DIM   1024
#define NPAD  1024

#define WAIT_VM(N) asm volatile("s_waitcnt vmcnt(" #N ")" ::: "memory")
#define BARRIER()  asm volatile("s_barrier" ::: "memory")

// ---- f16 helpers ----
__device__ __forceinline__ u16 f2h(float f) {
    union { f16 h; u16 u; } v; v.h = (f16)f; return v.u;
}
__device__ __forceinline__ float h2f(u16 u) {
    union { u16 u; f16 h; } v; v.u = u; return (float)v.h;
}

// ---- async global->LDS, 16B/lane (dest = wave-uniform base + lane*16) ----
__device__ __forceinline__ void gl16(const u16* g, char* l) {
    __builtin_amdgcn_global_load_lds(
        (const __attribute__((address_space(1))) unsigned int*)g,
        (__attribute__((address_space(3))) unsigned int*)l, 16, 0, 0);
}

#define MFMA16(a, b, c) __builtin_amdgcn_mfma_f32_16x16x32_f16(a, b, c, 0, 0, 0)

// ---------------------------------------------------------------------------
// prep kernels (unchanged from round 3)
// ---------------------------------------------------------------------------
__global__ __launch_bounds__(256) void prep_x(const float4* __restrict__ x4,
                                              u16* __restrict__ xh, int n4) {
    int stride = gridDim.x * blockDim.x;
    for (int i = blockIdx.x * blockDim.x + threadIdx.x; i < n4; i += stride) {
        float4 v = x4[i];
        *(ushort4*)&xh[(size_t)i * 4] =
            make_ushort4(f2h(v.x), f2h(v.y), f2h(v.z), f2h(v.w));
    }
}

__global__ __launch_bounds__(256) void prep_t(const float* __restrict__ t,
                                              u16* __restrict__ th) {
    int i = blockIdx.x * 256 + threadIdx.x;
    int node = i >> 10;
    float v = (node < 1023) ? t[i] : 0.0f;
    th[i] = f2h(v);
}

__global__ __launch_bounds__(256) void prep_lt(const float* __restrict__ L,
                                               u16* __restrict__ LT) {
    __shared__ float tile[32][33];
    int bx = blockIdx.x, by = blockIdx.y;
    int tx = threadIdx.x & 31, ty = threadIdx.x >> 5;
#pragma unroll
    for (int r = 0; r < 4; r++)
        tile[ty + 8 * r][tx] = L[(size_t)(by * 32 + ty + 8 * r) * 1024 + bx * 32 + tx];
    __syncthreads();
#pragma unroll
    for (int r = 0; r < 4; r++)
        LT[(size_t)(bx * 32 + ty + 8 * r) * 1024 + by * 32 + tx] =
            f2h(tile[tx][ty + 8 * r]);
}

// bijective XCD swizzle: 512 blocks, 64 per XCD; same row-panel's 4 col-tiles
// stay on one XCD L2.
__device__ __forceinline__ void block_map(int bid, int& rb, int& cb) {
    int lid = (bid & 7) * 64 + (bid >> 3);
    rb = (lid >> 2) << 8;
    cb = (lid & 3) << 8;
}

// ---------------------------------------------------------------------------
// 8-phase 256x256 GEMM core. A,B row-major [rows][1024] f16. K = NT*64.
// 8 waves: wave (wm = wid>>2, wn = wid&3) owns rows wm*128+[0,128),
// cols wn*64+[0,64). acc[8][4] f32x4 (m-frag, n-frag).
// LDS 128KiB: A slots [0,64K): dbuf*32768 + half*16384; B at +64K.
// Half slot = [128 rows][64 f16], row-XOR-swizzled: byte ^= (row&7)<<4.
// K-tile phases (template): P1{ds a0-3,b0-1; stage A-lo(t+1)} P2{ds b2-3;
// stage A-hi(t+1)} P3{ds a4-7; stage B-lo(t+2)} P4{stage B-hi(t+2); gate}.
// Each phase: [reads; stage; BAR; prio1; 16 MFMA; prio0; (gate); BAR].
// ---------------------------------------------------------------------------
template <int NT>
__device__ __forceinline__ void gemm_core8(const u16* __restrict__ Ap,
                                           const u16* __restrict__ Bp,
                                           int rb, int cb, char* lds,
                                           f32x4 acc[8][4])
{
    const int t = threadIdx.x, wid = t >> 6, lane = t & 63;
    const int wm = wid >> 2, wn = wid & 3;
    const int mr = lane & 15, kg = lane >> 4;

    // --- staging source (pre-swizzled: global k-block = lds-block ^ (row&7)) ---
    const int tr = t >> 3;
    const unsigned koff = 8u * ((unsigned)((t & 7) ^ (tr & 7)));
    const unsigned sAlo = (unsigned)(rb + tr) * 1024u + koff;
    const unsigned sAhi = sAlo + 131072u;           // +128 rows
    const unsigned sBlo = (unsigned)(cb + tr) * 1024u + koff;
    const unsigned sBhi = sBlo + 131072u;

    // --- swizzled ds_read offsets: frag(m|n, ks) = base + idx*2048 + e[ks] ---
    const unsigned key = (unsigned)(mr & 7) << 4;
    const unsigned e0 = (unsigned)mr * 128u + (((unsigned)kg * 16u) ^ key);
    const unsigned e1 = (unsigned)mr * 128u + ((64u + (unsigned)kg * 16u) ^ key);
    const unsigned bbase = (unsigned)(wn & 1) * 8192u;

#pragma unroll
    for (int m = 0; m < 8; ++m)
#pragma unroll
        for (int n = 0; n < 4; ++n) acc[m][n] = (f32x4){0.f, 0.f, 0.f, 0.f};

    auto stg = [&](int kt, unsigned srcb, const u16* G, int region, int halfo) {
        char* dst = lds + region + (kt & 1) * 32768 + halfo + t * 16;
        const u16* g = G + srcb + (unsigned)kt * 64u;
        gl16(g, dst);                 // rows [0,64) of the half
        gl16(g + 65536, dst + 8192);  // rows [64,128)
    };

    // prologue: tile0 fully; tile1 B-halves (A(1) staged in tile0's P1/P2)
    stg(0, sAlo, Ap, 0, 0);
    stg(0, sAhi, Ap, 0, 16384);
    stg(0, sBlo, Bp, 65536, 0);
    stg(0, sBhi, Bp, 65536, 16384);
    stg(1, sBlo, Bp, 65536, 0);
    stg(1, sBhi, Bp, 65536, 16384);
    WAIT_VM(4);       // tile0's 8 loads landed; B(1)'s 4 may be in flight
    BARRIER();

    f16x8 a[4][2], b[4][2];

#pragma unroll 1
    for (int kt = 0; kt < NT; ++kt) {
        char* LA = lds + (kt & 1) * 32768 + wm * 16384;
        char* LB = lds + 65536 + (kt & 1) * 32768 + (wn >> 1) * 16384;

        // ---------------- P1: ds a[m0-3], b[n0-1]; stage A-lo(t+1) ----------
#pragma unroll
        for (int i = 0; i < 4; ++i) {
            a[i][0] = *(const f16x8*)(LA + i * 2048 + e0);
            a[i][1] = *(const f16x8*)(LA + i * 2048 + e1);
        }
#pragma unroll
        for (int n = 0; n < 2; ++n) {
            b[n][0] = *(const f16x8*)(LB + bbase + n * 2048 + e0);
            b[n][1] = *(const f16x8*)(LB + bbase + n * 2048 + e1);
        }
        if (kt + 1 < NT) stg(kt + 1, sAlo, Ap, 0, 0);
        BARRIER();
        __builtin_amdgcn_s_setprio(1);
#pragma unroll
        for (int i = 0; i < 4; ++i)
#pragma unroll
            for (int n = 0; n < 2; ++n) {
                acc[i][n] = MFMA16(a[i][0], b[n][0], acc[i][n]);
                acc[i][n] = MFMA16(a[i][1], b[n][1], acc[i][n]);
            }
        __builtin_amdgcn_s_setprio(0);
        BARRIER();

        // ---------------- P2: ds b[n2-3]; stage A-hi(t+1) -------------------
#pragma unroll
        for (int n = 2; n < 4; ++n) {
            b[n][0] = *(const f16x8*)(LB + bbase + n * 2048 + e0);
            b[n][1] = *(const f16x8*)(LB + bbase + n * 2048 + e1);
        }
        if (kt + 1 < NT) stg(kt + 1, sAhi, Ap, 0, 16384);
        BARRIER();
        __builtin_amdgcn_s_setprio(1);
#pragma unroll
        for (int i = 0; i < 4; ++i)
#pragma unroll
            for (int n = 2; n < 4; ++n) {
                acc[i][n] = MFMA16(a[i][0], b[n][0], acc[i][n]);
                acc[i][n] = MFMA16(a[i][1], b[n][1], acc[i][n]);
            }
        __builtin_amdgcn_s_setprio(0);
        BARRIER();

        // ---------------- P3: ds a[m4-7]; stage B-lo(t+2) -------------------
#pragma unroll
        for (int i = 0; i < 4; ++i) {
            a[i][0] = *(const f16x8*)(LA + (4 + i) * 2048 + e0);
            a[i][1] = *(const f16x8*)(LA + (4 + i) * 2048 + e1);
        }
        if (kt + 2 < NT) stg(kt + 2, sBlo, Bp, 65536, 0);
        BARRIER();
        __builtin_amdgcn_s_setprio(1);
#pragma unroll
        for (int i = 0; i < 4; ++i)
#pragma unroll
            for (int n = 2; n < 4; ++n) {
                acc[4 + i][n] = MFMA16(a[i][0], b[n][0], acc[4 + i][n]);
                acc[4 + i][n] = MFMA16(a[i][1], b[n][1], acc[4 + i][n]);
            }
        __builtin_amdgcn_s_setprio(0);
        BARRIER();

        // ---------------- P4: stage B-hi(t+2); gate tile t+1 ----------------
        if (kt + 2 < NT) stg(kt + 2, sBhi, Bp, 65536, 16384);
        BARRIER();
        __builtin_amdgcn_s_setprio(1);
#pragma unroll
        for (int i = 0; i < 4; ++i)
#pragma unroll
            for (int n = 0; n < 2; ++n) {
                acc[4 + i][n] = MFMA16(a[i][0], b[n][0], acc[4 + i][n]);
                acc[4 + i][n] = MFMA16(a[i][1], b[n][1], acc[4 + i][n]);
            }
        __builtin_amdgcn_s_setprio(0);
        if (kt < NT - 1) {
            if (kt + 2 < NT) { WAIT_VM(4); } else { WAIT_VM(0); }
        }
        BARRIER();
    }
}

// ---------------------------------------------------------------------------
// GEMM1: d = sigmoid(X @ T^T), store {d, 1-d} f16 pairs
// ---------------------------------------------------------------------------
__global__ __launch_bounds__(512, 2) void gemm1_8p(
    const u16* __restrict__ Xh, const u16* __restrict__ Th,
    ushort2* __restrict__ dpair)
{
    __shared__ __align__(16) char lds[131072];
    int rb, cb;
    block_map(blockIdx.x, rb, cb);
    f32x4 acc[8][4];
    gemm_core8<16>(Xh, Th, rb, cb, lds, acc);

    const int lane = threadIdx.x & 63, wid = threadIdx.x >> 6;
    const int wm = wid >> 2, wn = wid & 3;
    const int mr = lane & 15, fq = (lane >> 4) * 4;
#pragma unroll
    for (int m = 0; m < 8; ++m)
#pragma unroll
        for (int j = 0; j < 4; ++j) {
            int grow = rb + wm * 128 + m * 16 + fq + j;
#pragma unroll
            for (int n = 0; n < 4; ++n) {
                int gcol = cb + wn * 64 + n * 16 + mr;
                float s = acc[m][n][j];
                float d = 1.0f / (1.0f + __expf(-s));
                dpair[(size_t)grow * NPAD + gcol] = make_ushort2(f2h(d), f2h(1.0f - d));
            }
        }
}

// ---------------------------------------------------------------------------
// GEMM2: logits = probs @ LT^T -> d_out (f32)
// ---------------------------------------------------------------------------
__global__ __launch_bounds__(512, 2) void gemm2_8p(
    const u16* __restrict__ P, const u16* __restrict__ LT,
    float* __restrict__ out)
{
    __shared__ __align__(16) char lds[131072];
    int rb, cb;
    block_map(blockIdx.x, rb, cb);
    f32x4 acc[8][4];
    gemm_core8<16>(P, LT, rb, cb, lds, acc);

    const int lane = threadIdx.x & 63, wid = threadIdx.x >> 6;
    const int wm = wid >> 2, wn = wid & 3;
    const int mr = lane & 15, fq = (lane >> 4) * 4;
#pragma unroll
    for (int m = 0; m < 8; ++m)
#pragma unroll
        for (int j = 0; j < 4; ++j) {
            int grow = rb + wm * 128 + m * 16 + fq + j;
#pragma unroll
            for (int n = 0; n < 4; ++n) {
                int gcol = cb + wn * 64 + n * 16 + mr;
                out[(size_t)grow * 1024 + gcol] = acc[m][n][j];
            }
        }
}

// ---------------------------------------------------------------------------
// tree expansion: one wave per row; lane l owns leaves l*16 .. l*16+15
// ---------------------------------------------------------------------------
__global__ __launch_bounds__(256) void probs_kernel(const ushort2* __restrict__ dpair,
                                                    u16* __restrict__ probs) {
    const int t = threadIdx.x, w = t >> 6, l = t & 63;
    const int row = (blockIdx.x << 2) + w;
    const ushort2* dp = dpair + (size_t)row * NPAD;

    float prod = 1.0f;
#pragma unroll
    for (int lev = 0; lev < 6; lev++) {
        int node = (1 << lev) - 1 + (l >> (6 - lev));
        int bit  = (l >> (5 - lev)) & 1;
        ushort2 v = dp[node];
        prod *= h2f(bit ? v.y : v.x);
    }
    ushort2 n6 = dp[63 + l];
    ushort2 n7[2], n8[4], n9[8];
#pragma unroll
    for (int j = 0; j < 2; j++) n7[j] = dp[127 + 2 * l + j];
#pragma unroll
    for (int j = 0; j < 4; j++) n8[j] = dp[255 + 4 * l + j];
#pragma unroll
    for (int j = 0; j < 8; j++) n9[j] = dp[511 + 8 * l + j];

    u16 outv[16];
#pragma unroll
    for (int j = 0; j < 16; j++) {
        float f6 = h2f((j >> 3) ? n6.y : n6.x);
        ushort2 v7 = n7[j >> 3];       float f7 = h2f(((j >> 2) & 1) ? v7.y : v7.x);
        ushort2 v8 = n8[j >> 2];       float f8 = h2f(((j >> 1) & 1) ? v8.y : v8.x);
        ushort2 v9 = n9[j >> 1];       float f9 = h2f((j & 1) ? v9.y : v9.x);
        outv[j] = f2h(prod * f6 * f7 * f8 * f9);
    }
    ushort4* po = (ushort4*)(probs + (size_t)row * 1024 + (l << 4));
#pragma unroll
    for (int q = 0; q < 4; q++)
        po[q] = make_ushort4(outv[4 * q], outv[4 * q + 1], outv[4 * q + 2], outv[4 * q + 3]);
}

// ---------------------------------------------------------------------------
// row softmax in-place on d_out
// ---------------------------------------------------------------------------
__global__ __launch_bounds__(256) void softmax_kernel(float* __restrict__ out) {
    __shared__ float red[8];
    const int t = threadIdx.x, w = t >> 6, l = t & 63;
    float4* o4 = (float4*)out;
    const size_t base = (size_t)blockIdx.x * 256;
    float4 v = o4[base + t];

    float m = fmaxf(fmaxf(v.x, v.y), fmaxf(v.z, v.w));
#pragma unroll
    for (int off = 32; off; off >>= 1) m = fmaxf(m, __shfl_xor(m, off));
    if (l == 0) red[w] = m;
    __syncthreads();
    m = fmaxf(fmaxf(red[0], red[1]), fmaxf(red[2], red[3]));

    float e0 = __expf(v.x - m), e1 = __expf(v.y - m);
    float e2 = __expf(v.z - m), e3 = __expf(v.w - m);
    float s = e0 + e1 + e2 + e3;
#pragma unroll
    for (int off = 32; off; off >>= 1) s += __shfl_xor(s, off);
    if (l == 0) red[4 + w] = s;
    __syncthreads();
    s = red[4] + red[5] + red[6] + red[7];
    float inv = 1.0f / s;
    o4[base + t] = make_float4(e0 * inv, e1 * inv, e2 * inv, e3 * inv);
}

// ---------------------------------------------------------------------------
extern "C" void kernel_launch(void* const* d_in, const int* in_sizes, int n_in,
                              void* d_out, int out_size, void* d_ws, size_t ws_size,
                              hipStream_t stream) {
    const float* x  = (const float*)d_in[0];
    const float* ft = (const float*)d_in[1];
    const float* lp = (const float*)d_in[2];
    float* out = (float*)d_out;
    char* ws = (char*)d_ws;

    // ws layout: Xh 64Mi | Th 2Mi | LT 2Mi | dpair 128Mi | probs 64Mi
    u16* Xh = (u16*)ws;
    u16* Th = (u16*)(ws + (size_t)67108864);
    u16* LT = Th + (size_t)NPAD * DIM;
    ushort2* dpair = (ushort2*)(ws + (size_t)67108864 + 2 * 2097152);
    u16* probs = (u16*)(ws + (size_t)67108864 + 2 * 2097152 + (size_t)BATCH * NPAD * 4);

    prep_x<<<4096, 256, 0, stream>>>((const float4*)x, Xh, BATCH * DIM / 4);
    prep_t<<<4096, 256, 0, stream>>>(ft, Th);
    prep_lt<<<dim3(32, 32), 256, 0, stream>>>(lp, LT);
    gemm1_8p<<<512, 512, 0, stream>>>(Xh, Th, dpair);
    probs_kernel<<<8192, 256, 0, stream>>>(dpair, probs);
    gemm2_8p<<<512, 512, 0, stream>>>(probs, LT, out);
    softmax_kernel<<<32768, 256, 0, stream>>>(out);
}